// Round 16
// baseline (259.726 us; speedup 1.0000x reference)
//
#include <hip/hip_runtime.h>
#include <math.h>

#define N_NODES 10000
#define N_GRAPHS 64
#define E_RAW 320000
#define E_ALL (E_RAW + N_NODES)   // 330000 edges incl. self-loops
#define NEG_SLOPE 0.2f
#define EPS 1e-16f
#define CAP 192                   // bucket-CSR capacity per dst (max deg ~75 for this input)

typedef unsigned short ushort_t;
typedef short short8 __attribute__((ext_vector_type(8)));
typedef float floatx4 __attribute__((ext_vector_type(4)));
typedef float floatx2 __attribute__((ext_vector_type(2)));

static __device__ __forceinline__ float bfl(unsigned u) {
  union { unsigned u; float f; } v; v.u = u << 16; return v.f;
}
static __device__ __forceinline__ float bfh(unsigned u) {
  union { unsigned u; float f; } v; v.u = u & 0xFFFF0000u; return v.f;
}
static __device__ __forceinline__ ushort_t f2bf(float f) {  // RNE
  union { float f; unsigned u; } v; v.f = f;
  unsigned r = v.u + 0x7FFFu + ((v.u >> 16) & 1u);
  return (ushort_t)(r >> 16);
}

// async global->LDS, 16 B per lane. ldsbase wave-uniform; lane i lands at ldsbase+16i.
static __device__ __forceinline__ void load16_lds(const ushort_t* gp, ushort_t* ldsbase, int lane) {
#if __has_builtin(__builtin_amdgcn_global_load_lds)
  __builtin_amdgcn_global_load_lds((const __attribute__((address_space(1))) void*)gp,
                                   (__attribute__((address_space(3))) void*)ldsbase, 16, 0, 0);
#else
  *(uint4*)(ldsbase + lane * 8) = *(const uint4*)gp;
#endif
}

// W [K,N] f32 -> bf16 swizzled to MFMA B-operand order.
// tile (kt,nt): 32k x 16n. lane l holds B[kt*32+(l>>4)*8+j][nt*16+(l&15)], j=0..7.
static __device__ __forceinline__ void swz_one(const float* __restrict__ W,
                                               ushort_t* __restrict__ Wsw,
                                               int idx, int K, int N) {
  int NT = N >> 4;
  int lane = idx & 63, tile = idx >> 6;
  int nt = tile % NT, kt = tile / NT;
  int n = nt * 16 + (lane & 15);
  int kb = kt * 32 + (lane >> 4) * 8;
  ushort4 lo, hi;
  lo.x = f2bf(W[(size_t)(kb + 0) * N + n]); lo.y = f2bf(W[(size_t)(kb + 1) * N + n]);
  lo.z = f2bf(W[(size_t)(kb + 2) * N + n]); lo.w = f2bf(W[(size_t)(kb + 3) * N + n]);
  hi.x = f2bf(W[(size_t)(kb + 4) * N + n]); hi.y = f2bf(W[(size_t)(kb + 5) * N + n]);
  hi.z = f2bf(W[(size_t)(kb + 6) * N + n]); hi.w = f2bf(W[(size_t)(kb + 7) * N + n]);
  *(ushort4*)(Wsw + (size_t)idx * 8) = lo;
  *(ushort4*)(Wsw + (size_t)idx * 8 + 4) = hi;
}

// ---------------- prep: zero + cvt + swizzles + batch-count (all parallel roles) ---------
__global__ __launch_bounds__(1024) void prep_k(const float* __restrict__ x,
                                               const int* __restrict__ batch,
                                               const float* __restrict__ W1,
                                               const float* __restrict__ W2,
                                               ushort_t* __restrict__ xb,
                                               ushort_t* __restrict__ W1sw,
                                               ushort_t* __restrict__ W2sw,
                                               float* __restrict__ zero0,
                                               int* __restrict__ poolcnt) {
  __shared__ int shm[N_GRAPHS];
  const int b = blockIdx.x, t = threadIdx.x;
  if (b < 49) {                              // zero block (float4): 49548 float4s
    int i4 = b * 1024 + t;
    if (i4 < 49548) *(float4*)(zero0 + i4 * 4) = make_float4(0.f, 0.f, 0.f, 0.f);
  } else if (b == 49) {                      // batch count
    if (t < N_GRAPHS) shm[t] = 0;
    __syncthreads();
    for (int n = t; n < N_NODES; n += 1024) atomicAdd(&shm[batch[n]], 1);
    __syncthreads();
    if (t < N_GRAPHS) poolcnt[t] = shm[t];
  } else if (b < 363) {                      // cvt x -> bf16 (1,280,000 elems)
    int i4 = (b - 50) * 1024 + t;
    if (i4 < 320000) {
      float4 v = *(const float4*)(x + (size_t)i4 * 4);
      ushort4 o;
      o.x = f2bf(v.x); o.y = f2bf(v.y); o.z = f2bf(v.z); o.w = f2bf(v.w);
      *(ushort4*)(xb + (size_t)i4 * 4) = o;
    }
  } else if (b < 379) {                      // swizzle W1 [128,1024]
    int idx = (b - 363) * 1024 + t;
    if (idx < 16384) swz_one(W1, W1sw, idx, 128, 1024);
  } else {                                   // swizzle W2 [1024,128]
    int idx = (b - 379) * 1024 + t;
    if (idx < 16384) swz_one(W2, W2sw, idx, 1024, 128);
  }
}

// ---------------- GEMM layer 1 (+ fused bucket-CSR fill) ---------------------------------
// blocks [0,632): gemm 128x128 tile, 4 waves 2x2, K=128 staged once; [632,1922): fill.
__global__ __launch_bounds__(256) void g1f_k(const ushort_t* __restrict__ A,
                                             const ushort_t* __restrict__ Bsw,
                                             ushort_t* __restrict__ Cb,
                                             const float* __restrict__ aS,
                                             const float* __restrict__ aD,
                                             float* __restrict__ asO,
                                             float* __restrict__ adO,
                                             const int* __restrict__ ei,
                                             int* __restrict__ degc,
                                             int* __restrict__ csr) {
  __shared__ ushort_t Albuf[32 * 512];     // 32 KB
  __shared__ float epi[4][16][68];         // 17.4 KB
  const int bid = blockIdx.x, t = threadIdx.x;
  if (bid >= 632) {                        // ---- bucket fill path ----
    int e = (bid - 632) * 256 + t;
    if (e < E_ALL) {
      int s, d;
      if (e < E_RAW) { s = ei[e]; d = ei[E_RAW + e]; }
      else           { s = d = e - E_RAW; }
      int pos = atomicAdd(&degc[d], 1);
      if (pos < CAP) csr[d * CAP + pos] = s;
    }
    return;
  }
  const int M = N_NODES, K = 128, NT = 64;
  const int lane = t & 63, w = t >> 6;
  const int wm = w >> 1, wn = w & 1;
  const int m0 = (bid >> 3) * 128;
  const int n0 = (bid & 7) * 128;
  const int g = lane >> 4, l16 = lane & 15;

  #pragma unroll
  for (int i = 0; i < 8; i++) {
    int tile = w * 8 + i;
    int mtl = tile >> 2, kt = tile & 3;
    int r = m0 + mtl * 16 + l16; r = r < M ? r : M - 1;
    load16_lds(A + (size_t)r * K + kt * 32 + g * 8, &Albuf[tile * 512], lane);
  }
  __syncthreads();

  floatx4 acc[4][4] = {};
  #pragma unroll
  for (int kt = 0; kt < 4; kt++) {
    short8 a[4], b[4];
    #pragma unroll
    for (int mi = 0; mi < 4; mi++)
      a[mi] = *(const short8*)&Albuf[(((wm * 4 + mi) * 4 + kt) * 64 + lane) * 8];
    #pragma unroll
    for (int ni = 0; ni < 4; ni++) {
      int nt = (n0 >> 4) + wn * 4 + ni;
      b[ni] = *(const short8*)(Bsw + ((size_t)(kt * NT + nt) * 64 + lane) * 8);
    }
    #pragma unroll
    for (int mi = 0; mi < 4; mi++)
      #pragma unroll
      for (int ni = 0; ni < 4; ni++)
        acc[mi][ni] = __builtin_amdgcn_mfma_f32_16x16x32_bf16(a[mi], b[ni], acc[mi][ni], 0, 0, 0);
  }

  const int h = bid & 7;                   // block spans exactly one head
  const int r = lane >> 2, c0 = (lane & 3) * 16;
  const int colh = wn * 64 + c0;
  float asc[16], adc[16];
  #pragma unroll
  for (int c = 0; c < 16; c++) { asc[c] = aS[h * 128 + colh + c]; adc[c] = aD[h * 128 + colh + c]; }
  #pragma unroll
  for (int mi = 0; mi < 4; mi++) {
    #pragma unroll
    for (int ni = 0; ni < 4; ni++)
      #pragma unroll
      for (int reg = 0; reg < 4; reg++)
        epi[w][g * 4 + reg][ni * 16 + l16] = acc[mi][ni][reg];
    float4 v0 = *(float4*)&epi[w][r][c0];
    float4 v1 = *(float4*)&epi[w][r][c0 + 4];
    float4 v2 = *(float4*)&epi[w][r][c0 + 8];
    float4 v3 = *(float4*)&epi[w][r][c0 + 12];
    float vr[16] = {v0.x,v0.y,v0.z,v0.w, v1.x,v1.y,v1.z,v1.w,
                    v2.x,v2.y,v2.z,v2.w, v3.x,v3.y,v3.z,v3.w};
    int grow = m0 + wm * 64 + mi * 16 + r;
    float sp = 0.f, dp = 0.f;
    ushort_t hv[16];
    #pragma unroll
    for (int c = 0; c < 16; c++) {
      sp = fmaf(vr[c], asc[c], sp);
      dp = fmaf(vr[c], adc[c], dp);
      hv[c] = f2bf(vr[c]);
    }
    sp += __shfl_xor(sp, 1); sp += __shfl_xor(sp, 2);
    dp += __shfl_xor(dp, 1); dp += __shfl_xor(dp, 2);
    if (grow < M) {
      uint4 u0, u1;
      u0.x = (unsigned)hv[0] | ((unsigned)hv[1] << 16);
      u0.y = (unsigned)hv[2] | ((unsigned)hv[3] << 16);
      u0.z = (unsigned)hv[4] | ((unsigned)hv[5] << 16);
      u0.w = (unsigned)hv[6] | ((unsigned)hv[7] << 16);
      u1.x = (unsigned)hv[8] | ((unsigned)hv[9] << 16);
      u1.y = (unsigned)hv[10] | ((unsigned)hv[11] << 16);
      u1.z = (unsigned)hv[12] | ((unsigned)hv[13] << 16);
      u1.w = (unsigned)hv[14] | ((unsigned)hv[15] << 16);
      ushort_t* cp = Cb + (size_t)grow * 1024 + (bid & 7) * 128 + wn * 64 + c0;
      *(uint4*)cp = u0;
      *(uint4*)(cp + 8) = u1;
      if ((lane & 3) == 0) {
        atomicAdd(&asO[grow * 8 + h], sp);
        atomicAdd(&adO[grow * 8 + h], dp);
      }
    }
  }
}

// ---------------- GEMM layer 2: [10000,1024] @ [1024,128], 32-row tiles, grid 313 --------
__global__ __launch_bounds__(256) void gemm2_k(const ushort_t* __restrict__ A,
                                               const ushort_t* __restrict__ Bsw,
                                               ushort_t* __restrict__ Cb,
                                               const float* __restrict__ aS,
                                               const float* __restrict__ aD,
                                               float* __restrict__ asO,
                                               float* __restrict__ adO) {
  const int M = N_NODES, K = 1024, NT = 8;
  __shared__ ushort_t Albuf[8 * 512];      // 8 KB per chunk
  __shared__ float epi[4][16][68];
  const int t = threadIdx.x, lane = t & 63, w = t >> 6;
  const int wm = w >> 1, wn = w & 1;
  const int mb0 = blockIdx.x * 32;
  const int g = lane >> 4, l16 = lane & 15;

  floatx4 acc[4] = {};
  for (int ch = 0; ch < 8; ch++) {
    #pragma unroll
    for (int i = 0; i < 2; i++) {
      int tile = w * 2 + i;
      int mtl = tile >> 2, kt = tile & 3;
      int r = mb0 + mtl * 16 + l16; r = r < M ? r : M - 1;
      load16_lds(A + (size_t)r * K + (ch * 4 + kt) * 32 + g * 8, &Albuf[tile * 512], lane);
    }
    __syncthreads();
    #pragma unroll
    for (int ks = 0; ks < 4; ks++) {
      short8 a = *(const short8*)&Albuf[(((wm * 4 + ks)) * 64 + lane) * 8];
      #pragma unroll
      for (int ni = 0; ni < 4; ni++) {
        int nt = wn * 4 + ni, ktg = ch * 4 + ks;
        short8 b = *(const short8*)(Bsw + ((size_t)(ktg * NT + nt) * 64 + lane) * 8);
        acc[ni] = __builtin_amdgcn_mfma_f32_16x16x32_bf16(a, b, acc[ni], 0, 0, 0);
      }
    }
    __syncthreads();
  }

  const int r = lane >> 2, c0 = (lane & 3) * 16;
  const int colh = wn * 64 + c0;
  float asc[16], adc[16];
  #pragma unroll
  for (int c = 0; c < 16; c++) { asc[c] = aS[colh + c]; adc[c] = aD[colh + c]; }
  #pragma unroll
  for (int ni = 0; ni < 4; ni++)
    #pragma unroll
    for (int reg = 0; reg < 4; reg++)
      epi[w][g * 4 + reg][ni * 16 + l16] = acc[ni][reg];
  float4 v0 = *(float4*)&epi[w][r][c0];
  float4 v1 = *(float4*)&epi[w][r][c0 + 4];
  float4 v2 = *(float4*)&epi[w][r][c0 + 8];
  float4 v3 = *(float4*)&epi[w][r][c0 + 12];
  float vr[16] = {v0.x,v0.y,v0.z,v0.w, v1.x,v1.y,v1.z,v1.w,
                  v2.x,v2.y,v2.z,v2.w, v3.x,v3.y,v3.z,v3.w};
  int grow = mb0 + wm * 16 + r;
  float sp = 0.f, dp = 0.f;
  ushort_t hv[16];
  #pragma unroll
  for (int c = 0; c < 16; c++) {
    sp = fmaf(vr[c], asc[c], sp);
    dp = fmaf(vr[c], adc[c], dp);
    hv[c] = f2bf(vr[c]);
  }
  sp += __shfl_xor(sp, 1); sp += __shfl_xor(sp, 2);
  dp += __shfl_xor(dp, 1); dp += __shfl_xor(dp, 2);
  if (grow < M) {
    uint4 u0, u1;
    u0.x = (unsigned)hv[0] | ((unsigned)hv[1] << 16);
    u0.y = (unsigned)hv[2] | ((unsigned)hv[3] << 16);
    u0.z = (unsigned)hv[4] | ((unsigned)hv[5] << 16);
    u0.w = (unsigned)hv[6] | ((unsigned)hv[7] << 16);
    u1.x = (unsigned)hv[8] | ((unsigned)hv[9] << 16);
    u1.y = (unsigned)hv[10] | ((unsigned)hv[11] << 16);
    u1.z = (unsigned)hv[12] | ((unsigned)hv[13] << 16);
    u1.w = (unsigned)hv[14] | ((unsigned)hv[15] << 16);
    ushort_t* cp = Cb + (size_t)grow * 128 + colh;
    *(uint4*)cp = u0;
    *(uint4*)(cp + 8) = u1;
    if ((lane & 3) == 0) {
      atomicAdd(&asO[grow], sp);
      atomicAdd(&adO[grow], dp);
    }
  }
}

// ---------------- layer-1 softmax + aggregation, head-sliced for XCD-local L2 -----------
// one block (64 thr) per (dst, head); bid&7 = head -> XCD-local 2.56 MB slice.
// Gather: half-wave per edge; lane owns 4 channels (8 B dwordx2), packed f32 math.
__global__ __launch_bounds__(64) void agg1_k(const ushort_t* __restrict__ xlb,
                                             const float* __restrict__ as1,
                                             const float* __restrict__ ad1,
                                             const float* __restrict__ b1,
                                             const int* __restrict__ degc,
                                             const int* __restrict__ csr,
                                             ushort_t* __restrict__ out) {
  const int bid = blockIdx.x, t = threadIdx.x;
  const int h = bid & 7, dst = bid >> 3;
  int deg = degc[dst]; deg = deg < CAP ? deg : CAP;
  const int beg = dst * CAP;
  const int degp = (deg + 7) & ~7;
  __shared__ uint2 pr[CAP];        // {row byte offset, alpha bits}
  float adh = ad1[dst * 8 + h];
  if (deg <= 64) {
    bool act = t < deg;
    int s = act ? csr[beg + t] : 0;
    float lg = -1e30f;
    if (act) {
      float v = as1[s * 8 + h] + adh;
      lg = v > 0.f ? v : NEG_SLOPE * v;
    }
    float pm = lg;
    #pragma unroll
    for (int off = 32; off; off >>= 1) pm = fmaxf(pm, __shfl_xor(pm, off));
    float ex = act ? __expf(lg - pm) : 0.f;
    float ps = ex;
    #pragma unroll
    for (int off = 32; off; off >>= 1) ps += __shfl_xor(ps, off);
    float inv = 1.0f / (ps + EPS);
    if (t < degp) pr[t] = act ? make_uint2((unsigned)(s * 2048), __float_as_uint(ex * inv))
                              : make_uint2(0u, 0u);
    __syncthreads();
  } else {
    __shared__ int ssg[CAP];
    __shared__ float alg[CAP];
    for (int e = t; e < deg; e += 64) ssg[e] = csr[beg + e];
    __syncthreads();
    float pm = -1e30f;
    for (int e = t; e < deg; e += 64) {
      float v = as1[ssg[e] * 8 + h] + adh;
      v = v > 0.f ? v : NEG_SLOPE * v;
      alg[e] = v;
      pm = fmaxf(pm, v);
    }
    #pragma unroll
    for (int off = 32; off; off >>= 1) pm = fmaxf(pm, __shfl_xor(pm, off));
    __syncthreads();
    float ps = 0.f;
    for (int e = t; e < deg; e += 64) ps += __expf(alg[e] - pm);
    #pragma unroll
    for (int off = 32; off; off >>= 1) ps += __shfl_xor(ps, off);
    float inv = 1.0f / (ps + EPS);
    for (int e = t; e < deg; e += 64)
      pr[e] = make_uint2((unsigned)(ssg[e] * 2048), __float_as_uint(__expf(alg[e] - pm) * inv));
    for (int e = deg + t; e < degp; e += 64) pr[e] = make_uint2(0u, 0u);
    __syncthreads();
  }
  // gather: half (t>>5) owns edges e0+2j+half; lane l32 owns channels h*128+4*l32..+3
  const int half = t >> 5, l32 = t & 31;
  const char* xbase = (const char*)xlb;
  const unsigned toff = (unsigned)(h * 256 + 8 * l32);
  floatx2 accA[4] = {}, accB[4] = {};
  for (int e0 = 0; e0 < degp; e0 += 8) {
    #pragma unroll
    for (int jp = 0; jp < 4; jp++) {
      uint2 p = pr[e0 + 2 * jp + half];
      uint2 u = *(const uint2*)(xbase + (p.x + toff));
      float a = __uint_as_float(p.y);
      floatx2 av = {a, a};
      floatx2 lo = {bfl(u.x), bfh(u.x)};
      floatx2 hi = {bfl(u.y), bfh(u.y)};
      accA[jp] += av * lo;
      accB[jp] += av * hi;
    }
  }
  floatx2 sA = (accA[0] + accA[1]) + (accA[2] + accA[3]);
  floatx2 sB = (accB[0] + accB[1]) + (accB[2] + accB[3]);
  sA.x += __shfl_xor(sA.x, 32); sA.y += __shfl_xor(sA.y, 32);
  sB.x += __shfl_xor(sB.x, 32); sB.y += __shfl_xor(sB.y, 32);
  if (half == 0) {
    int o = h * 128 + 4 * l32;
    float c0v = sA.x + b1[o];
    float c1v = sA.y + b1[o + 1];
    float c2v = sB.x + b1[o + 2];
    float c3v = sB.y + b1[o + 3];
    c0v = c0v > 0.f ? c0v : (__expf(c0v) - 1.0f);   // ELU
    c1v = c1v > 0.f ? c1v : (__expf(c1v) - 1.0f);
    c2v = c2v > 0.f ? c2v : (__expf(c2v) - 1.0f);
    c3v = c3v > 0.f ? c3v : (__expf(c3v) - 1.0f);
    uint2 up;
    up.x = (unsigned)f2bf(c0v) | ((unsigned)f2bf(c1v) << 16);
    up.y = (unsigned)f2bf(c2v) | ((unsigned)f2bf(c3v) << 16);
    *(uint2*)(out + (size_t)dst * 1024 + o) = up;
  }
}

// ---------------- layer-2 softmax + aggregation + bias + ELU + pooling ----------------
// same half-wave / packed structure; row stride 256 B. No cross-block sync.
__global__ __launch_bounds__(64) void agg2_k(const ushort_t* __restrict__ xlb2,
                                             const float* __restrict__ as2,
                                             const float* __restrict__ ad2,
                                             const float* __restrict__ b2,
                                             const int* __restrict__ degc,
                                             const int* __restrict__ csr,
                                             const int* __restrict__ batch,
                                             float* __restrict__ poolsum) {
  int dst = blockIdx.x, t = threadIdx.x;
  int deg = degc[dst]; deg = deg < CAP ? deg : CAP;
  int beg = dst * CAP;
  const int degp = (deg + 7) & ~7;
  float adv = ad2[dst];
  __shared__ uint2 pr[CAP];
  if (deg <= 64) {
    bool act = t < deg;
    int s = act ? csr[beg + t] : 0;
    float lg = -1e30f;
    if (act) {
      float v = as2[s] + adv;
      lg = v > 0.f ? v : NEG_SLOPE * v;
    }
    float pm = lg;
    #pragma unroll
    for (int off = 32; off; off >>= 1) pm = fmaxf(pm, __shfl_xor(pm, off));
    float ex = act ? __expf(lg - pm) : 0.f;
    float ps = ex;
    #pragma unroll
    for (int off = 32; off; off >>= 1) ps += __shfl_xor(ps, off);
    float inv = 1.0f / (ps + EPS);
    if (t < degp) pr[t] = act ? make_uint2((unsigned)(s * 256), __float_as_uint(ex * inv))
                              : make_uint2(0u, 0u);
    __syncthreads();
  } else {
    __shared__ int ssg[CAP];
    __shared__ float alg[CAP];
    for (int e = t; e < deg; e += 64) ssg[e] = csr[beg + e];
    __syncthreads();
    float pm = -1e30f;
    for (int e = t; e < deg; e += 64) {
      float v = as2[ssg[e]] + adv;
      v = v > 0.f ? v : NEG_SLOPE * v;
      alg[e] = v;
      pm = fmaxf(pm, v);
    }
    #pragma unroll
    for (int off = 32; off; off >>= 1) pm = fmaxf(pm, __shfl_xor(pm, off));
    __syncthreads();
    float ps = 0.f;
    for (int e = t; e < deg; e += 64) ps += __expf(alg[e] - pm);
    #pragma unroll
    for (int off = 32; off; off >>= 1) ps += __shfl_xor(ps, off);
    float inv = 1.0f / (ps + EPS);
    for (int e = t; e < deg; e += 64)
      pr[e] = make_uint2((unsigned)(ssg[e] * 256), __float_as_uint(__expf(alg[e] - pm) * inv));
    for (int e = deg + t; e < degp; e += 64) pr[e] = make_uint2(0u, 0u);
    __syncthreads();
  }
  const int half = t >> 5, l32 = t & 31;
  const char* xbase = (const char*)xlb2;
  const unsigned toff = (unsigned)(8 * l32);
  floatx2 accA[4] = {}, accB[4] = {};
  for (int e0 = 0; e0 < degp; e0 += 8) {
    #pragma unroll
    for (int jp = 0; jp < 4; jp++) {
      uint2 p = pr[e0 + 2 * jp + half];
      uint2 u = *(const uint2*)(xbase + (p.x + toff));
      float a = __uint_as_float(p.y);
      floatx2 av = {a, a};
      floatx2 lo = {bfl(u.x), bfh(u.x)};
      floatx2 hi = {bfl(u.y), bfh(u.y)};
      accA[jp] += av * lo;
      accB[jp] += av * hi;
    }
  }
  floatx2 sA = (accA[0] + accA[1]) + (accA[2] + accA[3]);
  floatx2 sB = (accB[0] + accB[1]) + (accB[2] + accB[3]);
  sA.x += __shfl_xor(sA.x, 32); sA.y += __shfl_xor(sA.y, 32);
  sB.x += __shfl_xor(sB.x, 32); sB.y += __shfl_xor(sB.y, 32);
  if (half == 0) {
    int o = 4 * l32;
    float c0v = sA.x + b2[o];
    float c1v = sA.y + b2[o + 1];
    float c2v = sB.x + b2[o + 2];
    float c3v = sB.y + b2[o + 3];
    c0v = c0v > 0.f ? c0v : (__expf(c0v) - 1.0f);
    c1v = c1v > 0.f ? c1v : (__expf(c1v) - 1.0f);
    c2v = c2v > 0.f ? c2v : (__expf(c2v) - 1.0f);
    c3v = c3v > 0.f ? c3v : (__expf(c3v) - 1.0f);
    int g = batch[dst];
    atomicAdd(&poolsum[g * 128 + o],     c0v);
    atomicAdd(&poolsum[g * 128 + o + 1], c1v);
    atomicAdd(&poolsum[g * 128 + o + 2], c2v);
    atomicAdd(&poolsum[g * 128 + o + 3], c3v);
  }
}

// ---------------- pooled MLP head ----------------
__global__ __launch_bounds__(128) void final_k(const float* __restrict__ poolsum,
                                               const int* __restrict__ cnt,
                                               const float* __restrict__ l1w,
                                               const float* __restrict__ l1b,
                                               const float* __restrict__ l2w,
                                               const float* __restrict__ l2b,
                                               float* __restrict__ out) {
  int g = blockIdx.x, t = threadIdx.x;
  __shared__ float pooled[128];
  float c = fmaxf((float)cnt[g], 1.0f);
  pooled[t] = poolsum[g * 128 + t] / c;
  __syncthreads();
  float acc = l1b[t];
  for (int i = 0; i < 128; i++) acc = fmaf(pooled[i], l1w[i * 128 + t], acc);
  acc = fmaxf(acc, 0.0f);  // ReLU
  float p = acc * l2w[t];
  #pragma unroll
  for (int off = 32; off; off >>= 1) p += __shfl_down(p, off);
  __shared__ float r[2];
  if ((t & 63) == 0) r[t >> 6] = p;
  __syncthreads();
  if (t == 0) out[g] = r[0] + r[1] + l2b[0];
}

extern "C" void kernel_launch(void* const* d_in, const int* in_sizes, int n_in,
                              void* d_out, int out_size, void* d_ws, size_t ws_size,
                              hipStream_t stream) {
  const float* x    = (const float*)d_in[0];
  const int*   ei   = (const int*)d_in[1];
  const int*   batch= (const int*)d_in[2];
  const float* W1   = (const float*)d_in[3];
  const float* aS1  = (const float*)d_in[4];
  const float* aD1  = (const float*)d_in[5];
  const float* b1   = (const float*)d_in[6];
  const float* W2   = (const float*)d_in[7];
  const float* aS2  = (const float*)d_in[8];
  const float* aD2  = (const float*)d_in[9];
  const float* b2   = (const float*)d_in[10];
  const float* l1w  = (const float*)d_in[11];
  const float* l1b  = (const float*)d_in[12];
  const float* l2w  = (const float*)d_in[13];
  const float* l2b  = (const float*)d_in[14];
  float* out = (float*)d_out;

  // workspace layout (~55 MB)
  ushort_t* xlb1   = (ushort_t*)d_ws;                 // 10,240,000 bf16
  ushort_t* h1b    = xlb1 + 10240000;                 // 10,240,000 bf16
  ushort_t* xlb2   = h1b + 10240000;                  // 1,280,000 bf16
  ushort_t* xb     = xlb2 + 1280000;                  // 1,280,000 bf16
  ushort_t* W1sw   = xb + 1280000;                    // 131,072 bf16
  ushort_t* W2sw   = W1sw + 131072;                   // 131,072 bf16
  float*    zero0  = (float*)(W2sw + 131072);         // ---- zero block (198,192 words) ----
  float*    as1    = zero0;                           // 80,000 f
  float*    ad1    = as1 + 80000;                     // 80,000 f
  float*    as2    = ad1 + 80000;                     // 10,000 f
  float*    ad2    = as2 + 10000;                     // 10,000 f
  float*    poolsum= ad2 + 10000;                     // 8,192 f
  int*      degc   = (int*)(poolsum + 8192);          // 10,000 i ---- zero block end ----
  int*      poolcnt= degc + 10000;                    // 64 i
  int*      csr    = poolcnt + 64;                    // 1,920,000 i (bucket CSR)

  // 1. prep: zero + cvt + swizzles + batch count (all parallel)
  prep_k<<<395, 1024, 0, stream>>>(x, batch, W1, W2, xb, W1sw, W2sw, zero0, poolcnt);
  // 2. layer-1 GEMM (+ fused logits) + bucket-CSR fill
  g1f_k<<<632 + 1290, 256, 0, stream>>>(xb, W1sw, xlb1, aS1, aD1, as1, ad1, ei, degc, csr);
  // 3. layer-1 softmax-aggregate, head-sliced (dst,head) blocks
  agg1_k<<<N_NODES * 8, 64, 0, stream>>>(xlb1, as1, ad1, b1, degc, csr, h1b);
  // 4. layer-2 GEMM (+ fused logits)
  gemm2_k<<<313, 256, 0, stream>>>(h1b, W2sw, xlb2, aS2, aD2, as2, ad2);
  // 5. layer-2 softmax-aggregate + pooling
  agg2_k<<<N_NODES, 64, 0, stream>>>(xlb2, as2, ad2, b2, degc, csr, batch, poolsum);
  // 6. head
  final_k<<<N_GRAPHS, 128, 0, stream>>>(poolsum, poolcnt, l1w, l1b, l2w, l2b, out);
}

// Round 17
// 217.322 us; speedup vs baseline: 1.1951x; 1.1951x over previous
//
#include <hip/hip_runtime.h>
#include <math.h>

#define N_NODES 10000
#define N_GRAPHS 64
#define E_RAW 320000
#define E_ALL (E_RAW + N_NODES)   // 330000 edges incl. self-loops
#define NEG_SLOPE 0.2f
#define EPS 1e-16f
#define CAP 192                   // bucket-CSR capacity per dst (max deg ~75 for this input)

typedef unsigned short ushort_t;
typedef short short8 __attribute__((ext_vector_type(8)));
typedef float floatx4 __attribute__((ext_vector_type(4)));

static __device__ __forceinline__ float bfl(unsigned u) {
  union { unsigned u; float f; } v; v.u = u << 16; return v.f;
}
static __device__ __forceinline__ float bfh(unsigned u) {
  union { unsigned u; float f; } v; v.u = u & 0xFFFF0000u; return v.f;
}
static __device__ __forceinline__ ushort_t f2bf(float f) {  // RNE
  union { float f; unsigned u; } v; v.f = f;
  unsigned r = v.u + 0x7FFFu + ((v.u >> 16) & 1u);
  return (ushort_t)(r >> 16);
}

// async global->LDS, 16 B per lane. ldsbase wave-uniform; lane i lands at ldsbase+16i.
static __device__ __forceinline__ void load16_lds(const ushort_t* gp, ushort_t* ldsbase, int lane) {
#if __has_builtin(__builtin_amdgcn_global_load_lds)
  __builtin_amdgcn_global_load_lds((const __attribute__((address_space(1))) void*)gp,
                                   (__attribute__((address_space(3))) void*)ldsbase, 16, 0, 0);
#else
  *(uint4*)(ldsbase + lane * 8) = *(const uint4*)gp;
#endif
}

// W [K,N] f32 -> bf16 swizzled to MFMA B-operand order.
// tile (kt,nt): 32k x 16n. lane l holds B[kt*32+(l>>4)*8+j][nt*16+(l&15)], j=0..7.
static __device__ __forceinline__ void swz_one(const float* __restrict__ W,
                                               ushort_t* __restrict__ Wsw,
                                               int idx, int K, int N) {
  int NT = N >> 4;
  int lane = idx & 63, tile = idx >> 6;
  int nt = tile % NT, kt = tile / NT;
  int n = nt * 16 + (lane & 15);
  int kb = kt * 32 + (lane >> 4) * 8;
  ushort4 lo, hi;
  lo.x = f2bf(W[(size_t)(kb + 0) * N + n]); lo.y = f2bf(W[(size_t)(kb + 1) * N + n]);
  lo.z = f2bf(W[(size_t)(kb + 2) * N + n]); lo.w = f2bf(W[(size_t)(kb + 3) * N + n]);
  hi.x = f2bf(W[(size_t)(kb + 4) * N + n]); hi.y = f2bf(W[(size_t)(kb + 5) * N + n]);
  hi.z = f2bf(W[(size_t)(kb + 6) * N + n]); hi.w = f2bf(W[(size_t)(kb + 7) * N + n]);
  *(ushort4*)(Wsw + (size_t)idx * 8) = lo;
  *(ushort4*)(Wsw + (size_t)idx * 8 + 4) = hi;
}

// ---------------- prep: zero + cvt + swizzles + batch-count (all parallel roles) ---------
__global__ __launch_bounds__(1024) void prep_k(const float* __restrict__ x,
                                               const int* __restrict__ batch,
                                               const float* __restrict__ W1,
                                               const float* __restrict__ W2,
                                               ushort_t* __restrict__ xb,
                                               ushort_t* __restrict__ W1sw,
                                               ushort_t* __restrict__ W2sw,
                                               float* __restrict__ zero0,
                                               int* __restrict__ poolcnt) {
  __shared__ int shm[N_GRAPHS];
  const int b = blockIdx.x, t = threadIdx.x;
  if (b < 49) {                              // zero block (float4): 49548 float4s
    int i4 = b * 1024 + t;
    if (i4 < 49548) *(float4*)(zero0 + i4 * 4) = make_float4(0.f, 0.f, 0.f, 0.f);
  } else if (b == 49) {                      // batch count
    if (t < N_GRAPHS) shm[t] = 0;
    __syncthreads();
    for (int n = t; n < N_NODES; n += 1024) atomicAdd(&shm[batch[n]], 1);
    __syncthreads();
    if (t < N_GRAPHS) poolcnt[t] = shm[t];
  } else if (b < 363) {                      // cvt x -> bf16 (1,280,000 elems)
    int i4 = (b - 50) * 1024 + t;
    if (i4 < 320000) {
      float4 v = *(const float4*)(x + (size_t)i4 * 4);
      ushort4 o;
      o.x = f2bf(v.x); o.y = f2bf(v.y); o.z = f2bf(v.z); o.w = f2bf(v.w);
      *(ushort4*)(xb + (size_t)i4 * 4) = o;
    }
  } else if (b < 379) {                      // swizzle W1 [128,1024]
    int idx = (b - 363) * 1024 + t;
    if (idx < 16384) swz_one(W1, W1sw, idx, 128, 1024);
  } else {                                   // swizzle W2 [1024,128]
    int idx = (b - 379) * 1024 + t;
    if (idx < 16384) swz_one(W2, W2sw, idx, 1024, 128);
  }
}

// ---------------- GEMM layer 1 (+ fused bucket-CSR fill) ---------------------------------
// blocks [0,632): gemm 128x128 tile, 4 waves 2x2, K=128 staged once; [632,1922): fill.
__global__ __launch_bounds__(256) void g1f_k(const ushort_t* __restrict__ A,
                                             const ushort_t* __restrict__ Bsw,
                                             ushort_t* __restrict__ Cb,
                                             const float* __restrict__ aS,
                                             const float* __restrict__ aD,
                                             float* __restrict__ asO,
                                             float* __restrict__ adO,
                                             const int* __restrict__ ei,
                                             int* __restrict__ degc,
                                             int* __restrict__ csr) {
  __shared__ ushort_t Albuf[32 * 512];     // 32 KB
  __shared__ float epi[4][16][68];         // 17.4 KB
  const int bid = blockIdx.x, t = threadIdx.x;
  if (bid >= 632) {                        // ---- bucket fill path ----
    int e = (bid - 632) * 256 + t;
    if (e < E_ALL) {
      int s, d;
      if (e < E_RAW) { s = ei[e]; d = ei[E_RAW + e]; }
      else           { s = d = e - E_RAW; }
      int pos = atomicAdd(&degc[d], 1);
      if (pos < CAP) csr[d * CAP + pos] = s;
    }
    return;
  }
  const int M = N_NODES, K = 128, NT = 64;
  const int lane = t & 63, w = t >> 6;
  const int wm = w >> 1, wn = w & 1;
  const int m0 = (bid >> 3) * 128;
  const int n0 = (bid & 7) * 128;
  const int g = lane >> 4, l16 = lane & 15;

  #pragma unroll
  for (int i = 0; i < 8; i++) {
    int tile = w * 8 + i;
    int mtl = tile >> 2, kt = tile & 3;
    int r = m0 + mtl * 16 + l16; r = r < M ? r : M - 1;
    load16_lds(A + (size_t)r * K + kt * 32 + g * 8, &Albuf[tile * 512], lane);
  }
  __syncthreads();

  floatx4 acc[4][4] = {};
  #pragma unroll
  for (int kt = 0; kt < 4; kt++) {
    short8 a[4], b[4];
    #pragma unroll
    for (int mi = 0; mi < 4; mi++)
      a[mi] = *(const short8*)&Albuf[(((wm * 4 + mi) * 4 + kt) * 64 + lane) * 8];
    #pragma unroll
    for (int ni = 0; ni < 4; ni++) {
      int nt = (n0 >> 4) + wn * 4 + ni;
      b[ni] = *(const short8*)(Bsw + ((size_t)(kt * NT + nt) * 64 + lane) * 8);
    }
    #pragma unroll
    for (int mi = 0; mi < 4; mi++)
      #pragma unroll
      for (int ni = 0; ni < 4; ni++)
        acc[mi][ni] = __builtin_amdgcn_mfma_f32_16x16x32_bf16(a[mi], b[ni], acc[mi][ni], 0, 0, 0);
  }

  const int h = bid & 7;                   // block spans exactly one head
  const int r = lane >> 2, c0 = (lane & 3) * 16;
  const int colh = wn * 64 + c0;
  float asc[16], adc[16];
  #pragma unroll
  for (int c = 0; c < 16; c++) { asc[c] = aS[h * 128 + colh + c]; adc[c] = aD[h * 128 + colh + c]; }
  #pragma unroll
  for (int mi = 0; mi < 4; mi++) {
    #pragma unroll
    for (int ni = 0; ni < 4; ni++)
      #pragma unroll
      for (int reg = 0; reg < 4; reg++)
        epi[w][g * 4 + reg][ni * 16 + l16] = acc[mi][ni][reg];
    float4 v0 = *(float4*)&epi[w][r][c0];
    float4 v1 = *(float4*)&epi[w][r][c0 + 4];
    float4 v2 = *(float4*)&epi[w][r][c0 + 8];
    float4 v3 = *(float4*)&epi[w][r][c0 + 12];
    float vr[16] = {v0.x,v0.y,v0.z,v0.w, v1.x,v1.y,v1.z,v1.w,
                    v2.x,v2.y,v2.z,v2.w, v3.x,v3.y,v3.z,v3.w};
    int grow = m0 + wm * 64 + mi * 16 + r;
    float sp = 0.f, dp = 0.f;
    ushort_t hv[16];
    #pragma unroll
    for (int c = 0; c < 16; c++) {
      sp = fmaf(vr[c], asc[c], sp);
      dp = fmaf(vr[c], adc[c], dp);
      hv[c] = f2bf(vr[c]);
    }
    sp += __shfl_xor(sp, 1); sp += __shfl_xor(sp, 2);
    dp += __shfl_xor(dp, 1); dp += __shfl_xor(dp, 2);
    if (grow < M) {
      uint4 u0, u1;
      u0.x = (unsigned)hv[0] | ((unsigned)hv[1] << 16);
      u0.y = (unsigned)hv[2] | ((unsigned)hv[3] << 16);
      u0.z = (unsigned)hv[4] | ((unsigned)hv[5] << 16);
      u0.w = (unsigned)hv[6] | ((unsigned)hv[7] << 16);
      u1.x = (unsigned)hv[8] | ((unsigned)hv[9] << 16);
      u1.y = (unsigned)hv[10] | ((unsigned)hv[11] << 16);
      u1.z = (unsigned)hv[12] | ((unsigned)hv[13] << 16);
      u1.w = (unsigned)hv[14] | ((unsigned)hv[15] << 16);
      ushort_t* cp = Cb + (size_t)grow * 1024 + (bid & 7) * 128 + wn * 64 + c0;
      *(uint4*)cp = u0;
      *(uint4*)(cp + 8) = u1;
      if ((lane & 3) == 0) {
        atomicAdd(&asO[grow * 8 + h], sp);
        atomicAdd(&adO[grow * 8 + h], dp);
      }
    }
  }
}

// ---------------- GEMM layer 2: [10000,1024] @ [1024,128], 32-row tiles, grid 313 --------
__global__ __launch_bounds__(256) void gemm2_k(const ushort_t* __restrict__ A,
                                               const ushort_t* __restrict__ Bsw,
                                               ushort_t* __restrict__ Cb,
                                               const float* __restrict__ aS,
                                               const float* __restrict__ aD,
                                               float* __restrict__ asO,
                                               float* __restrict__ adO) {
  const int M = N_NODES, K = 1024, NT = 8;
  __shared__ ushort_t Albuf[8 * 512];      // 8 KB per chunk
  __shared__ float epi[4][16][68];
  const int t = threadIdx.x, lane = t & 63, w = t >> 6;
  const int wm = w >> 1, wn = w & 1;
  const int mb0 = blockIdx.x * 32;
  const int g = lane >> 4, l16 = lane & 15;

  floatx4 acc[4] = {};
  for (int ch = 0; ch < 8; ch++) {
    #pragma unroll
    for (int i = 0; i < 2; i++) {
      int tile = w * 2 + i;
      int mtl = tile >> 2, kt = tile & 3;
      int r = mb0 + mtl * 16 + l16; r = r < M ? r : M - 1;
      load16_lds(A + (size_t)r * K + (ch * 4 + kt) * 32 + g * 8, &Albuf[tile * 512], lane);
    }
    __syncthreads();
    #pragma unroll
    for (int ks = 0; ks < 4; ks++) {
      short8 a = *(const short8*)&Albuf[(((wm * 4 + ks)) * 64 + lane) * 8];
      #pragma unroll
      for (int ni = 0; ni < 4; ni++) {
        int nt = wn * 4 + ni, ktg = ch * 4 + ks;
        short8 b = *(const short8*)(Bsw + ((size_t)(ktg * NT + nt) * 64 + lane) * 8);
        acc[ni] = __builtin_amdgcn_mfma_f32_16x16x32_bf16(a, b, acc[ni], 0, 0, 0);
      }
    }
    __syncthreads();
  }

  const int r = lane >> 2, c0 = (lane & 3) * 16;
  const int colh = wn * 64 + c0;
  float asc[16], adc[16];
  #pragma unroll
  for (int c = 0; c < 16; c++) { asc[c] = aS[colh + c]; adc[c] = aD[colh + c]; }
  #pragma unroll
  for (int ni = 0; ni < 4; ni++)
    #pragma unroll
    for (int reg = 0; reg < 4; reg++)
      epi[w][g * 4 + reg][ni * 16 + l16] = acc[ni][reg];
  float4 v0 = *(float4*)&epi[w][r][c0];
  float4 v1 = *(float4*)&epi[w][r][c0 + 4];
  float4 v2 = *(float4*)&epi[w][r][c0 + 8];
  float4 v3 = *(float4*)&epi[w][r][c0 + 12];
  float vr[16] = {v0.x,v0.y,v0.z,v0.w, v1.x,v1.y,v1.z,v1.w,
                  v2.x,v2.y,v2.z,v2.w, v3.x,v3.y,v3.z,v3.w};
  int grow = mb0 + wm * 16 + r;
  float sp = 0.f, dp = 0.f;
  ushort_t hv[16];
  #pragma unroll
  for (int c = 0; c < 16; c++) {
    sp = fmaf(vr[c], asc[c], sp);
    dp = fmaf(vr[c], adc[c], dp);
    hv[c] = f2bf(vr[c]);
  }
  sp += __shfl_xor(sp, 1); sp += __shfl_xor(sp, 2);
  dp += __shfl_xor(dp, 1); dp += __shfl_xor(dp, 2);
  if (grow < M) {
    uint4 u0, u1;
    u0.x = (unsigned)hv[0] | ((unsigned)hv[1] << 16);
    u0.y = (unsigned)hv[2] | ((unsigned)hv[3] << 16);
    u0.z = (unsigned)hv[4] | ((unsigned)hv[5] << 16);
    u0.w = (unsigned)hv[6] | ((unsigned)hv[7] << 16);
    u1.x = (unsigned)hv[8] | ((unsigned)hv[9] << 16);
    u1.y = (unsigned)hv[10] | ((unsigned)hv[11] << 16);
    u1.z = (unsigned)hv[12] | ((unsigned)hv[13] << 16);
    u1.w = (unsigned)hv[14] | ((unsigned)hv[15] << 16);
    ushort_t* cp = Cb + (size_t)grow * 128 + colh;
    *(uint4*)cp = u0;
    *(uint4*)(cp + 8) = u1;
    if ((lane & 3) == 0) {
      atomicAdd(&asO[grow], sp);
      atomicAdd(&adO[grow], dp);
    }
  }
}

// ---------------- layer-1 softmax + aggregation, head-sliced for XCD-local L2 -----------
// one block (64 thr) per (dst, head); bid&7 = head -> XCD-local 2.56 MB slice.
// Gather: packed (offset,alpha) pairs, padded to x8, unroll 8, 4 split accumulator pairs.
__global__ __launch_bounds__(64) void agg1_k(const ushort_t* __restrict__ xlb,
                                             const float* __restrict__ as1,
                                             const float* __restrict__ ad1,
                                             const float* __restrict__ b1,
                                             const int* __restrict__ degc,
                                             const int* __restrict__ csr,
                                             ushort_t* __restrict__ out) {
  const int bid = blockIdx.x, t = threadIdx.x;
  const int h = bid & 7, dst = bid >> 3;
  int deg = degc[dst]; deg = deg < CAP ? deg : CAP;
  const int beg = dst * CAP;
  const int degp = (deg + 7) & ~7;
  __shared__ uint2 pr[CAP];        // {row byte offset, alpha bits}
  float adh = ad1[dst * 8 + h];
  if (deg <= 64) {
    bool act = t < deg;
    int s = act ? csr[beg + t] : 0;
    float lg = -1e30f;
    if (act) {
      float v = as1[s * 8 + h] + adh;
      lg = v > 0.f ? v : NEG_SLOPE * v;
    }
    float pm = lg;
    #pragma unroll
    for (int off = 32; off; off >>= 1) pm = fmaxf(pm, __shfl_xor(pm, off));
    float ex = act ? __expf(lg - pm) : 0.f;
    float ps = ex;
    #pragma unroll
    for (int off = 32; off; off >>= 1) ps += __shfl_xor(ps, off);
    float inv = 1.0f / (ps + EPS);
    if (t < degp) pr[t] = act ? make_uint2((unsigned)(s * 2048), __float_as_uint(ex * inv))
                              : make_uint2(0u, 0u);
    __syncthreads();
  } else {
    __shared__ int ssg[CAP];
    __shared__ float alg[CAP];
    for (int e = t; e < deg; e += 64) ssg[e] = csr[beg + e];
    __syncthreads();
    float pm = -1e30f;
    for (int e = t; e < deg; e += 64) {
      float v = as1[ssg[e] * 8 + h] + adh;
      v = v > 0.f ? v : NEG_SLOPE * v;
      alg[e] = v;
      pm = fmaxf(pm, v);
    }
    #pragma unroll
    for (int off = 32; off; off >>= 1) pm = fmaxf(pm, __shfl_xor(pm, off));
    __syncthreads();
    float ps = 0.f;
    for (int e = t; e < deg; e += 64) ps += __expf(alg[e] - pm);
    #pragma unroll
    for (int off = 32; off; off >>= 1) ps += __shfl_xor(ps, off);
    float inv = 1.0f / (ps + EPS);
    for (int e = t; e < deg; e += 64)
      pr[e] = make_uint2((unsigned)(ssg[e] * 2048), __float_as_uint(__expf(alg[e] - pm) * inv));
    for (int e = deg + t; e < degp; e += 64) pr[e] = make_uint2(0u, 0u);
    __syncthreads();
  }
  // gather: thread t owns channels h*128 + 2t, +1; 8 edges per outer iter, split accs
  const char* xbase = (const char*)xlb;
  const unsigned toff = (unsigned)(h * 256 + 4 * t);
  float accA[4] = {}, accB[4] = {};
  for (int e0 = 0; e0 < degp; e0 += 8) {
    #pragma unroll
    for (int j = 0; j < 8; j++) {
      uint2 p = pr[e0 + j];
      unsigned u = *(const unsigned*)(xbase + (p.x + toff));
      float a = __uint_as_float(p.y);
      accA[j & 3] = fmaf(a, bfl(u), accA[j & 3]);
      accB[j & 3] = fmaf(a, bfh(u), accB[j & 3]);
    }
  }
  float acc0 = (accA[0] + accA[1]) + (accA[2] + accA[3]);
  float acc1 = (accB[0] + accB[1]) + (accB[2] + accB[3]);
  int o = h * 128 + 2 * t;
  float v0 = acc0 + b1[o];
  float v1 = acc1 + b1[o + 1];
  v0 = v0 > 0.f ? v0 : (__expf(v0) - 1.0f);   // ELU
  v1 = v1 > 0.f ? v1 : (__expf(v1) - 1.0f);
  unsigned up = (unsigned)f2bf(v0) | ((unsigned)f2bf(v1) << 16);
  *(unsigned*)(out + (size_t)dst * 1024 + o) = up;
}

// ---------------- layer-2 softmax + aggregation + bias + ELU + pooling ----------------
// same packed-pair / fast-path / ILP-8 structure; row stride 256 B. No cross-block sync.
__global__ __launch_bounds__(64) void agg2_k(const ushort_t* __restrict__ xlb2,
                                             const float* __restrict__ as2,
                                             const float* __restrict__ ad2,
                                             const float* __restrict__ b2,
                                             const int* __restrict__ degc,
                                             const int* __restrict__ csr,
                                             const int* __restrict__ batch,
                                             float* __restrict__ poolsum) {
  int dst = blockIdx.x, t = threadIdx.x;
  int deg = degc[dst]; deg = deg < CAP ? deg : CAP;
  int beg = dst * CAP;
  const int degp = (deg + 7) & ~7;
  float adv = ad2[dst];
  __shared__ uint2 pr[CAP];
  if (deg <= 64) {
    bool act = t < deg;
    int s = act ? csr[beg + t] : 0;
    float lg = -1e30f;
    if (act) {
      float v = as2[s] + adv;
      lg = v > 0.f ? v : NEG_SLOPE * v;
    }
    float pm = lg;
    #pragma unroll
    for (int off = 32; off; off >>= 1) pm = fmaxf(pm, __shfl_xor(pm, off));
    float ex = act ? __expf(lg - pm) : 0.f;
    float ps = ex;
    #pragma unroll
    for (int off = 32; off; off >>= 1) ps += __shfl_xor(ps, off);
    float inv = 1.0f / (ps + EPS);
    if (t < degp) pr[t] = act ? make_uint2((unsigned)(s * 256), __float_as_uint(ex * inv))
                              : make_uint2(0u, 0u);
    __syncthreads();
  } else {
    __shared__ int ssg[CAP];
    __shared__ float alg[CAP];
    for (int e = t; e < deg; e += 64) ssg[e] = csr[beg + e];
    __syncthreads();
    float pm = -1e30f;
    for (int e = t; e < deg; e += 64) {
      float v = as2[ssg[e]] + adv;
      v = v > 0.f ? v : NEG_SLOPE * v;
      alg[e] = v;
      pm = fmaxf(pm, v);
    }
    #pragma unroll
    for (int off = 32; off; off >>= 1) pm = fmaxf(pm, __shfl_xor(pm, off));
    __syncthreads();
    float ps = 0.f;
    for (int e = t; e < deg; e += 64) ps += __expf(alg[e] - pm);
    #pragma unroll
    for (int off = 32; off; off >>= 1) ps += __shfl_xor(ps, off);
    float inv = 1.0f / (ps + EPS);
    for (int e = t; e < deg; e += 64)
      pr[e] = make_uint2((unsigned)(ssg[e] * 256), __float_as_uint(__expf(alg[e] - pm) * inv));
    for (int e = deg + t; e < degp; e += 64) pr[e] = make_uint2(0u, 0u);
    __syncthreads();
  }
  const char* xbase = (const char*)xlb2;
  const unsigned toff = (unsigned)(4 * t);
  float accA[4] = {}, accB[4] = {};
  for (int e0 = 0; e0 < degp; e0 += 8) {
    #pragma unroll
    for (int j = 0; j < 8; j++) {
      uint2 p = pr[e0 + j];
      unsigned u = *(const unsigned*)(xbase + (p.x + toff));
      float a = __uint_as_float(p.y);
      accA[j & 3] = fmaf(a, bfl(u), accA[j & 3]);
      accB[j & 3] = fmaf(a, bfh(u), accB[j & 3]);
    }
  }
  float acc0 = (accA[0] + accA[1]) + (accA[2] + accA[3]);
  float acc1 = (accB[0] + accB[1]) + (accB[2] + accB[3]);
  int c0 = 2 * t;
  float v0 = acc0 + b2[c0];
  float v1 = acc1 + b2[c0 + 1];
  v0 = v0 > 0.f ? v0 : (__expf(v0) - 1.0f);
  v1 = v1 > 0.f ? v1 : (__expf(v1) - 1.0f);
  int g = batch[dst];
  atomicAdd(&poolsum[g * 128 + c0], v0);
  atomicAdd(&poolsum[g * 128 + c0 + 1], v1);
}

// ---------------- pooled MLP head ----------------
__global__ __launch_bounds__(128) void final_k(const float* __restrict__ poolsum,
                                               const int* __restrict__ cnt,
                                               const float* __restrict__ l1w,
                                               const float* __restrict__ l1b,
                                               const float* __restrict__ l2w,
                                               const float* __restrict__ l2b,
                                               float* __restrict__ out) {
  int g = blockIdx.x, t = threadIdx.x;
  __shared__ float pooled[128];
  float c = fmaxf((float)cnt[g], 1.0f);
  pooled[t] = poolsum[g * 128 + t] / c;
  __syncthreads();
  float acc = l1b[t];
  for (int i = 0; i < 128; i++) acc = fmaf(pooled[i], l1w[i * 128 + t], acc);
  acc = fmaxf(acc, 0.0f);  // ReLU
  float p = acc * l2w[t];
  #pragma unroll
  for (int off = 32; off; off >>= 1) p += __shfl_down(p, off);
  __shared__ float r[2];
  if ((t & 63) == 0) r[t >> 6] = p;
  __syncthreads();
  if (t == 0) out[g] = r[0] + r[1] + l2b[0];
}

extern "C" void kernel_launch(void* const* d_in, const int* in_sizes, int n_in,
                              void* d_out, int out_size, void* d_ws, size_t ws_size,
                              hipStream_t stream) {
  const float* x    = (const float*)d_in[0];
  const int*   ei   = (const int*)d_in[1];
  const int*   batch= (const int*)d_in[2];
  const float* W1   = (const float*)d_in[3];
  const float* aS1  = (const float*)d_in[4];
  const float* aD1  = (const float*)d_in[5];
  const float* b1   = (const float*)d_in[6];
  const float* W2   = (const float*)d_in[7];
  const float* aS2  = (const float*)d_in[8];
  const float* aD2  = (const float*)d_in[9];
  const float* b2   = (const float*)d_in[10];
  const float* l1w  = (const float*)d_in[11];
  const float* l1b  = (const float*)d_in[12];
  const float* l2w  = (const float*)d_in[13];
  const float* l2b  = (const float*)d_in[14];
  float* out = (float*)d_out;

  // workspace layout (~55 MB)
  ushort_t* xlb1   = (ushort_t*)d_ws;                 // 10,240,000 bf16
  ushort_t* h1b    = xlb1 + 10240000;                 // 10,240,000 bf16
  ushort_t* xlb2   = h1b + 10240000;                  // 1,280,000 bf16
  ushort_t* xb     = xlb2 + 1280000;                  // 1,280,000 bf16
  ushort_t* W1sw   = xb + 1280000;                    // 131,072 bf16
  ushort_t* W2sw   = W1sw + 131072;                   // 131,072 bf16
  float*    zero0  = (float*)(W2sw + 131072);         // ---- zero block (198,192 words) ----
  float*    as1    = zero0;                           // 80,000 f
  float*    ad1    = as1 + 80000;                     // 80,000 f
  float*    as2    = ad1 + 80000;                     // 10,000 f
  float*    ad2    = as2 + 10000;                     // 10,000 f
  float*    poolsum= ad2 + 10000;                     // 8,192 f
  int*      degc   = (int*)(poolsum + 8192);          // 10,000 i ---- zero block end ----
  int*      poolcnt= degc + 10000;                    // 64 i
  int*      csr    = poolcnt + 64;                    // 1,920,000 i (bucket CSR)

  // 1. prep: zero + cvt + swizzles + batch count (all parallel)
  prep_k<<<395, 1024, 0, stream>>>(x, batch, W1, W2, xb, W1sw, W2sw, zero0, poolcnt);
  // 2. layer-1 GEMM (+ fused logits) + bucket-CSR fill
  g1f_k<<<632 + 1290, 256, 0, stream>>>(xb, W1sw, xlb1, aS1, aD1, as1, ad1, ei, degc, csr);
  // 3. layer-1 softmax-aggregate, head-sliced (dst,head) blocks
  agg1_k<<<N_NODES * 8, 64, 0, stream>>>(xlb1, as1, ad1, b1, degc, csr, h1b);
  // 4. layer-2 GEMM (+ fused logits)
  gemm2_k<<<313, 256, 0, stream>>>(h1b, W2sw, xlb2, aS2, aD2, as2, ad2);
  // 5. layer-2 softmax-aggregate + pooling
  agg2_k<<<N_NODES, 64, 0, stream>>>(xlb2, as2, ad2, b2, degc, csr, batch, poolsum);
  // 6. head
  final_k<<<N_GRAPHS, 128, 0, stream>>>(poolsum, poolcnt, l1w, l1b, l2w, l2b, out);
}